// Round 4
// baseline (240.169 us; speedup 1.0000x reference)
//
#include <hip/hip_runtime.h>

// Problem shape (fixed by setup_inputs): B=1024, T=2048, A=64.
// Outputs concatenated flat: equity_curve [B][T+1] then net_return [B][T].
#define PB 1024
#define PT 2048
#define NW 16          // waves per block (one block per row)
#define LW 128         // timesteps per wave = PT/NW
#define NIT 32         // LW/4 iterations per wave

static constexpr float TX_COST = 0.001f;

// One block per row. Phase A is a pure streaming pass with NO loop-carried
// state: each wave-iteration loads a contiguous 1 KiB block = 4 timestep
// rows (float4/lane), computes the combined per-lane partial of
// (port_return - TX*turnover), reduces within 4-lane groups (2 shfl_xor),
// and parks 4 partials per timestep in LDS. Phase B (after one barrier)
// sums partials, does one 64-lane scan per 64-t chunk, folds cross-wave
// chunk products, and streams both outputs with coalesced dword stores.
__global__ __launch_bounds__(1024) void fused_sim(
    const float4* __restrict__ A4, const float4* __restrict__ R4,
    float* __restrict__ eq,       // [B][T+1] region of d_out
    float* __restrict__ nr_out)   // [B][T]   region of d_out
{
    __shared__ float s_part[PT][4];   // 32 KiB: 4 partials per timestep
    __shared__ float s_P[NW];         // per-wave (128-t chunk) products

    int b    = blockIdx.x;
    int w    = threadIdx.x >> 6;
    int lane = threadIdx.x & 63;
    int tg   = lane >> 4;             // which of the 4 rows in the 1 KiB block
    int cq   = lane & 15;             // which float4 of the row
    int t0   = w * LW;

    const size_t rowbase = ((size_t)b * PT + t0) * 16;   // float4 units

#pragma unroll 8
    for (int i = 0; i < NIT; ++i) {
        int trow = t0 + i * 4 + tg;
        size_t idx = rowbase + (size_t)i * 64 + lane;
        float4 a4 = A4[idx];
        float4 r4 = R4[idx];
        float4 pa4;
        if (trow == 0) pa4 = make_float4(0.f, 0.f, 0.f, 0.f);
        else           pa4 = A4[idx - 16];          // row t-1: L1/L2 hit

        float d = fabsf(a4.x - pa4.x) + fabsf(a4.y - pa4.y)
                + fabsf(a4.z - pa4.z) + fabsf(a4.w - pa4.w);
        float p = a4.x * r4.x + a4.y * r4.y + a4.z * r4.z + a4.w * r4.w;
        float q = fmaf(d, -TX_COST, p);   // combined partial (linear)
        q += __shfl_xor(q, 1, 64);
        q += __shfl_xor(q, 2, 64);
        // lanes with (cq&3)==0 hold the sum over their 4-lane group
        if ((cq & 3) == 0) s_part[trow][cq >> 2] = q;
    }
    __syncthreads();

    // ---- Phase B: lane handles timesteps t0+lane and t0+64+lane ----
    int ta = t0 + lane;
    int tb = ta + 64;
    float4 g0 = *(const float4*)s_part[ta];
    float4 g1 = *(const float4*)s_part[tb];
    float nr0 = (g0.x + g0.y) + (g0.z + g0.w);
    float nr1 = (g1.x + g1.y) + (g1.z + g1.w);
    float f0 = 1.0f + nr0;
    float f1 = 1.0f + nr1;

    float p0 = f0;                     // inclusive scan over 64 lanes
#pragma unroll
    for (int off = 1; off < 64; off <<= 1) {
        float u = __shfl_up(p0, off, 64);
        if (lane >= off) p0 *= u;
    }
    float tot0 = __shfl(p0, 63, 64);
    float p1v = f1;
#pragma unroll
    for (int off = 1; off < 64; off <<= 1) {
        float u = __shfl_up(p1v, off, 64);
        if (lane >= off) p1v *= u;
    }
    float tot1 = __shfl(p1v, 63, 64);

    if (lane == 0) s_P[w] = tot0 * tot1;
    __syncthreads();

    float S = 1.0f;                    // cross-wave exclusive prefix (uniform)
    for (int j = 0; j < w; ++j) S *= s_P[j];

    float* eqrow = eq     + (size_t)b * (PT + 1);
    float* nrrow = nr_out + (size_t)b * PT;
    __builtin_nontemporal_store(S * p0,               &eqrow[1 + ta]);
    __builtin_nontemporal_store(S * tot0 * p1v,       &eqrow[1 + tb]);
    __builtin_nontemporal_store(nr0,                  &nrrow[ta]);
    __builtin_nontemporal_store(nr1,                  &nrrow[tb]);
    if (threadIdx.x == 0) __builtin_nontemporal_store(1.0f, &eqrow[0]);
}

extern "C" void kernel_launch(void* const* d_in, const int* in_sizes, int n_in,
                              void* d_out, int out_size, void* d_ws, size_t ws_size,
                              hipStream_t stream) {
    const float4* A4 = (const float4*)d_in[0];
    const float4* R4 = (const float4*)d_in[1];
    float* eq     = (float*)d_out;                       // [B][T+1]
    float* nr_out = eq + (size_t)PB * (PT + 1);          // [B][T]

    fused_sim<<<PB, 1024, 0, stream>>>(A4, R4, eq, nr_out);
}

// Round 5
// 198.137 us; speedup vs baseline: 1.2121x; 1.2121x over previous
//
#include <hip/hip_runtime.h>

// Problem shape (fixed by setup_inputs): B=1024, T=2048, A=64.
// Outputs concatenated flat: equity_curve [B][T+1] then net_return [B][T].
#define PB 1024
#define PT 2048
#define NW 8           // waves per block (one block per row)
#define LW 256         // timesteps per wave = PT/NW
#define NIT 64         // LW/4 iterations per wave

static constexpr float TX_COST = 0.001f;

// One block (8 waves) per row. Phase A: stateless streaming — wave w walks
// its 64 iterations in ROTATED order (hashed per-wave start) so the
// chip-wide instantaneous address set is decorrelated across HBM channels
// (all bases here are exact powers of two apart: R = A + 512 MiB, rows
// 512 KiB apart, chunks 32 KiB apart). Each iteration loads a contiguous
// 1 KiB block = 4 timestep rows (float4/lane), computes the combined
// per-lane partial of (port_return - TX*turnover), reduces within 4-lane
// groups, parks 4 partials/timestep in LDS. Phase B: per-wave 64-lane scans
// + cross-wave chunk-product prefix, coalesced nontemporal stores.
__global__ __launch_bounds__(512) void fused_sim(
    const float4* __restrict__ A4, const float4* __restrict__ R4,
    float* __restrict__ eq,       // [B][T+1] region of d_out
    float* __restrict__ nr_out)   // [B][T]   region of d_out
{
    __shared__ float s_part[PT][4];   // 32 KiB: 4 partials per timestep
    __shared__ float s_P[NW];         // per-wave (256-t chunk) products

    int b    = blockIdx.x;
    int w    = threadIdx.x >> 6;
    int lane = threadIdx.x & 63;
    int tg   = lane >> 4;             // which of the 4 rows in the 1 KiB block
    int cq   = lane & 15;             // which float4 of the row
    int t0   = w * LW;

    const size_t rowbase = ((size_t)b * PT + t0) * 16;   // float4 units
    int start = (b * 13 + w * 5) & (NIT - 1);            // per-wave rotation

#pragma unroll 4
    for (int ii = 0; ii < NIT; ++ii) {
        int i = (ii + start) & (NIT - 1);
        int trow = t0 + i * 4 + tg;
        size_t idx = rowbase + (size_t)i * 64 + lane;
        float4 a4 = A4[idx];
        float4 r4 = R4[idx];
        float4 pa4;
        if (trow == 0) pa4 = make_float4(0.f, 0.f, 0.f, 0.f);
        else           pa4 = A4[idx - 16];          // row t-1: L1/L2 hit

        float d = fabsf(a4.x - pa4.x) + fabsf(a4.y - pa4.y)
                + fabsf(a4.z - pa4.z) + fabsf(a4.w - pa4.w);
        float p = a4.x * r4.x + a4.y * r4.y + a4.z * r4.z + a4.w * r4.w;
        float q = fmaf(d, -TX_COST, p);   // combined partial (linear)
        q += __shfl_xor(q, 1, 64);
        q += __shfl_xor(q, 2, 64);
        if ((cq & 3) == 0) s_part[trow][cq >> 2] = q;
    }
    __syncthreads();

    // ---- Phase B: wave w scans timesteps [t0, t0+256) in 4 chunks of 64 ----
    float pv[4], nr[4], tot[4];
#pragma unroll
    for (int k = 0; k < 4; ++k) {
        int t = t0 + k * 64 + lane;
        float4 g = *(const float4*)s_part[t];
        nr[k] = (g.x + g.y) + (g.z + g.w);
        float p = 1.0f + nr[k];
#pragma unroll
        for (int off = 1; off < 64; off <<= 1) {
            float u = __shfl_up(p, off, 64);
            if (lane >= off) p *= u;
        }
        pv[k]  = p;
        tot[k] = __shfl(p, 63, 64);
    }
    if (lane == 0) s_P[w] = tot[0] * tot[1] * tot[2] * tot[3];
    __syncthreads();

    float S = 1.0f;                    // cross-wave exclusive prefix (uniform)
    for (int j = 0; j < w; ++j) S *= s_P[j];

    float* eqrow = eq     + (size_t)b * (PT + 1);
    float* nrrow = nr_out + (size_t)b * PT;
#pragma unroll
    for (int k = 0; k < 4; ++k) {
        int t = t0 + k * 64 + lane;
        __builtin_nontemporal_store(S * pv[k], &eqrow[1 + t]);
        __builtin_nontemporal_store(nr[k],     &nrrow[t]);
        S *= tot[k];
    }
    if (threadIdx.x == 0) __builtin_nontemporal_store(1.0f, &eqrow[0]);
}

extern "C" void kernel_launch(void* const* d_in, const int* in_sizes, int n_in,
                              void* d_out, int out_size, void* d_ws, size_t ws_size,
                              hipStream_t stream) {
    const float4* A4 = (const float4*)d_in[0];
    const float4* R4 = (const float4*)d_in[1];
    float* eq     = (float*)d_out;                       // [B][T+1]
    float* nr_out = eq + (size_t)PB * (PT + 1);          // [B][T]

    fused_sim<<<PB, 512, 0, stream>>>(A4, R4, eq, nr_out);
}

// Round 6
// 193.305 us; speedup vs baseline: 1.2424x; 1.0250x over previous
//
#include <hip/hip_runtime.h>

// Problem shape (fixed by setup_inputs): B=1024, T=2048, A=64.
// Outputs concatenated flat: equity_curve [B][T+1] then net_return [B][T].
#define PB 1024
#define PT 2048
#define NW 8           // waves per block (one block per row)
#define LW 256         // timesteps per wave = PT/NW
#define NIT 64         // LW/4 iterations per wave

static constexpr float TX_COST = 0.001f;

// One block (8 waves) per row. Phase A: stateless streaming in rotated
// iteration order (HBM channel decorrelation). Each iteration loads a
// contiguous 1 KiB block = 4 timestep rows (float4/lane). The previous
// timestep's allocation row comes from REGISTERS, not memory: within the
// block it lives in the tg-1 group's a4; across iterations the last row is
// carried. mix = (tg==3 ? carry : a4); one ds_bpermute per component with
// src lane (lane+48)&63 then delivers row t-1 to every lane. Only the
// chunk-start and rotation-wrap iterations (2 of 64, tg==0 lanes only)
// fall back to a global load. This removes the 512 MiB A-re-read stream
// (L2 hits) and 1/3 of VMEM instructions.
__global__ __launch_bounds__(512) void fused_sim(
    const float4* __restrict__ A4, const float4* __restrict__ R4,
    float* __restrict__ eq,       // [B][T+1] region of d_out
    float* __restrict__ nr_out)   // [B][T]   region of d_out
{
    __shared__ float s_part[PT][4];   // 32 KiB: 4 partials per timestep
    __shared__ float s_P[NW];         // per-wave (256-t chunk) products

    int b    = blockIdx.x;
    int w    = threadIdx.x >> 6;
    int lane = threadIdx.x & 63;
    int tg   = lane >> 4;             // which of the 4 rows in the 1 KiB block
    int cq   = lane & 15;             // which float4 of the row
    int t0   = w * LW;

    const size_t rowbase = ((size_t)b * PT + t0) * 16;   // float4 units
    int start = (b * 13 + w * 5) & (NIT - 1);            // per-wave rotation
    int srcl  = (lane + 48) & 63;                        // bpermute src lane

    float4 carry = make_float4(0.f, 0.f, 0.f, 0.f);

#pragma unroll 4
    for (int ii = 0; ii < NIT; ++ii) {
        int i = (ii + start) & (NIT - 1);
        int trow = t0 + i * 4 + tg;
        size_t idx = rowbase + (size_t)i * 64 + lane;
        float4 a4 = A4[idx];
        float4 r4 = R4[idx];

        // Row t-1 from registers. Source lane S=(L+48)&63: for L>=16 S is
        // the tg-1 group (current a4); for L<16 S is 48..63 (carry = prev
        // iteration's tg=3 row). mix per SOURCE lane's tg:
        float4 mix;
        mix.x = (tg == 3) ? carry.x : a4.x;
        mix.y = (tg == 3) ? carry.y : a4.y;
        mix.z = (tg == 3) ? carry.z : a4.z;
        mix.w = (tg == 3) ? carry.w : a4.w;
        float4 pa4;
        pa4.x = __shfl(mix.x, srcl, 64);
        pa4.y = __shfl(mix.y, srcl, 64);
        pa4.z = __shfl(mix.z, srcl, 64);
        pa4.w = __shfl(mix.w, srcl, 64);

        // Chunk start (i==0: prev row belongs to another wave) and rotation
        // wrap (ii==0: predecessor block not yet loaded): tg==0 lanes load.
        if ((ii == 0) | (i == 0)) {
            if (tg == 0) {
                if (trow == 0) pa4 = make_float4(0.f, 0.f, 0.f, 0.f);
                else           pa4 = A4[idx - 16];
            }
        }
        carry = a4;

        float d = fabsf(a4.x - pa4.x) + fabsf(a4.y - pa4.y)
                + fabsf(a4.z - pa4.z) + fabsf(a4.w - pa4.w);
        float p = a4.x * r4.x + a4.y * r4.y + a4.z * r4.z + a4.w * r4.w;
        float q = fmaf(d, -TX_COST, p);   // combined partial (linear)
        q += __shfl_xor(q, 1, 64);
        q += __shfl_xor(q, 2, 64);
        if ((cq & 3) == 0) s_part[trow][cq >> 2] = q;
    }
    __syncthreads();

    // ---- Phase B: wave w scans timesteps [t0, t0+256) in 4 chunks of 64 ----
    float pv[4], nr[4], tot[4];
#pragma unroll
    for (int k = 0; k < 4; ++k) {
        int t = t0 + k * 64 + lane;
        float4 g = *(const float4*)s_part[t];
        nr[k] = (g.x + g.y) + (g.z + g.w);
        float p = 1.0f + nr[k];
#pragma unroll
        for (int off = 1; off < 64; off <<= 1) {
            float u = __shfl_up(p, off, 64);
            if (lane >= off) p *= u;
        }
        pv[k]  = p;
        tot[k] = __shfl(p, 63, 64);
    }
    if (lane == 0) s_P[w] = tot[0] * tot[1] * tot[2] * tot[3];
    __syncthreads();

    float S = 1.0f;                    // cross-wave exclusive prefix (uniform)
    for (int j = 0; j < w; ++j) S *= s_P[j];

    float* eqrow = eq     + (size_t)b * (PT + 1);
    float* nrrow = nr_out + (size_t)b * PT;
#pragma unroll
    for (int k = 0; k < 4; ++k) {
        int t = t0 + k * 64 + lane;
        __builtin_nontemporal_store(S * pv[k], &eqrow[1 + t]);
        __builtin_nontemporal_store(nr[k],     &nrrow[t]);
        S *= tot[k];
    }
    if (threadIdx.x == 0) __builtin_nontemporal_store(1.0f, &eqrow[0]);
}

extern "C" void kernel_launch(void* const* d_in, const int* in_sizes, int n_in,
                              void* d_out, int out_size, void* d_ws, size_t ws_size,
                              hipStream_t stream) {
    const float4* A4 = (const float4*)d_in[0];
    const float4* R4 = (const float4*)d_in[1];
    float* eq     = (float*)d_out;                       // [B][T+1]
    float* nr_out = eq + (size_t)PB * (PT + 1);          // [B][T]

    fused_sim<<<PB, 512, 0, stream>>>(A4, R4, eq, nr_out);
}

// Round 8
// 173.702 us; speedup vs baseline: 1.3826x; 1.1129x over previous
//
#include <hip/hip_runtime.h>

// Problem shape (fixed by setup_inputs): B=1024, T=2048, A=64.
// Outputs concatenated flat: equity_curve [B][T+1] then net_return [B][T].
#define PB 1024
#define PT 2048
#define NW 8           // waves per block (one block per row)
#define LW 256         // timesteps per wave = PT/NW
#define NIT 64         // LW/4 iterations per wave

static constexpr float TX_COST = 0.001f;

typedef float fx4 __attribute__((ext_vector_type(4)));   // NT-load-compatible

// One block (8 waves) per row. Phase A: stateless streaming in rotated
// iteration order (HBM channel decorrelation), nontemporal float4 loads
// (read-once data: don't retain in L2/L3). Prev-timestep allocation row
// comes from registers via one cross-lane shuffle per component; only the
// chunk-start / rotation-wrap iterations (2 of 64, tg==0 lanes) fall back
// to a global load. Phase B: per-wave 64-lane scans + cross-wave
// chunk-product prefix, coalesced nontemporal stores.
__global__ __launch_bounds__(512) void fused_sim(
    const fx4* __restrict__ A4, const fx4* __restrict__ R4,
    float* __restrict__ eq,       // [B][T+1] region of d_out
    float* __restrict__ nr_out)   // [B][T]   region of d_out
{
    __shared__ float s_part[PT][4];   // 32 KiB: 4 partials per timestep
    __shared__ float s_P[NW];         // per-wave (256-t chunk) products

    int b    = blockIdx.x;
    int w    = threadIdx.x >> 6;
    int lane = threadIdx.x & 63;
    int tg   = lane >> 4;             // which of the 4 rows in the 1 KiB block
    int cq   = lane & 15;             // which float4 of the row
    int t0   = w * LW;

    const size_t rowbase = ((size_t)b * PT + t0) * 16;   // float4 units
    int start = (b * 13 + w * 5) & (NIT - 1);            // per-wave rotation
    int srcl  = (lane + 48) & 63;                        // shuffle src lane

    fx4 carry = (fx4)(0.f);

#pragma unroll 4
    for (int ii = 0; ii < NIT; ++ii) {
        int i = (ii + start) & (NIT - 1);
        int trow = t0 + i * 4 + tg;
        size_t idx = rowbase + (size_t)i * 64 + lane;
        fx4 a4 = __builtin_nontemporal_load(&A4[idx]);
        fx4 r4 = __builtin_nontemporal_load(&R4[idx]);

        // Row t-1 from registers. Source lane S=(L+48)&63: for L>=16 S is
        // the tg-1 group (current a4); for L<16 S is 48..63 (carry = prev
        // iteration's tg=3 row). mix per SOURCE lane's tg:
        fx4 mix;
        mix.x = (tg == 3) ? carry.x : a4.x;
        mix.y = (tg == 3) ? carry.y : a4.y;
        mix.z = (tg == 3) ? carry.z : a4.z;
        mix.w = (tg == 3) ? carry.w : a4.w;
        fx4 pa4;
        pa4.x = __shfl(mix.x, srcl, 64);
        pa4.y = __shfl(mix.y, srcl, 64);
        pa4.z = __shfl(mix.z, srcl, 64);
        pa4.w = __shfl(mix.w, srcl, 64);

        // Chunk start (i==0: prev row belongs to another wave) and rotation
        // wrap (ii==0: predecessor block not yet loaded): tg==0 lanes load.
        if ((ii == 0) | (i == 0)) {
            if (tg == 0) {
                if (trow == 0) pa4 = (fx4)(0.f);
                else           pa4 = A4[idx - 16];
            }
        }
        carry = a4;

        float d = fabsf(a4.x - pa4.x) + fabsf(a4.y - pa4.y)
                + fabsf(a4.z - pa4.z) + fabsf(a4.w - pa4.w);
        float p = a4.x * r4.x + a4.y * r4.y + a4.z * r4.z + a4.w * r4.w;
        float q = fmaf(d, -TX_COST, p);   // combined partial (linear)
        q += __shfl_xor(q, 1, 64);
        q += __shfl_xor(q, 2, 64);
        if ((cq & 3) == 0) s_part[trow][cq >> 2] = q;
    }
    __syncthreads();

    // ---- Phase B: wave w scans timesteps [t0, t0+256) in 4 chunks of 64 ----
    float pv[4], nr[4], tot[4];
#pragma unroll
    for (int k = 0; k < 4; ++k) {
        int t = t0 + k * 64 + lane;
        float4 g = *(const float4*)s_part[t];
        nr[k] = (g.x + g.y) + (g.z + g.w);
        float p = 1.0f + nr[k];
#pragma unroll
        for (int off = 1; off < 64; off <<= 1) {
            float u = __shfl_up(p, off, 64);
            if (lane >= off) p *= u;
        }
        pv[k]  = p;
        tot[k] = __shfl(p, 63, 64);
    }
    if (lane == 0) s_P[w] = tot[0] * tot[1] * tot[2] * tot[3];
    __syncthreads();

    float S = 1.0f;                    // cross-wave exclusive prefix (uniform)
    for (int j = 0; j < w; ++j) S *= s_P[j];

    float* eqrow = eq     + (size_t)b * (PT + 1);
    float* nrrow = nr_out + (size_t)b * PT;
#pragma unroll
    for (int k = 0; k < 4; ++k) {
        int t = t0 + k * 64 + lane;
        __builtin_nontemporal_store(S * pv[k], &eqrow[1 + t]);
        __builtin_nontemporal_store(nr[k],     &nrrow[t]);
        S *= tot[k];
    }
    if (threadIdx.x == 0) __builtin_nontemporal_store(1.0f, &eqrow[0]);
}

extern "C" void kernel_launch(void* const* d_in, const int* in_sizes, int n_in,
                              void* d_out, int out_size, void* d_ws, size_t ws_size,
                              hipStream_t stream) {
    const fx4* A4 = (const fx4*)d_in[0];
    const fx4* R4 = (const fx4*)d_in[1];
    float* eq     = (float*)d_out;                       // [B][T+1]
    float* nr_out = eq + (size_t)PB * (PT + 1);          // [B][T]

    fused_sim<<<PB, 512, 0, stream>>>(A4, R4, eq, nr_out);
}